// Round 1
// baseline (788.340 us; speedup 1.0000x reference)
//
#include <hip/hip_runtime.h>

#define N_ANCHORS 5000
#define N_CLASSES 80
#define OUT_COLS  (N_CLASSES + 4)   // 84
#define MAX_BOXES 300
#define NMS_THR   0.5f
#define SCORE_THR 0.05f
#define BLOCK     512
#define PER_THREAD 10               // ceil(5000/512) = 10
#define NWAVES    (BLOCK / 64)      // 8

// One block per class. Iterative argmax-select greedy NMS, all per-anchor
// state in registers (10 anchors/thread). 2 __syncthreads per iteration.
__global__ __launch_bounds__(BLOCK) void nms_kernel(const float* __restrict__ boxes,
                                                    const float* __restrict__ cls,
                                                    float* __restrict__ out) {
    const int c = blockIdx.x;
    const int tid = threadIdx.x;

    float sc[PER_THREAD];
    float bx1[PER_THREAD], by1[PER_THREAD], bx2[PER_THREAD], by2[PER_THREAD], bar[PER_THREAD];

    #pragma unroll
    for (int k = 0; k < PER_THREAD; ++k) {
        int j = tid + k * BLOCK;
        if (j < N_ANCHORS) {
            float x1 = boxes[j * 4 + 0];
            float y1 = boxes[j * 4 + 1];
            float x2 = boxes[j * 4 + 2];
            float y2 = boxes[j * 4 + 3];
            bx1[k] = x1; by1[k] = y1; bx2[k] = x2; by2[k] = y2;
            bar[k] = (x2 - x1) * (y2 - y1);
            float s = cls[j * N_CLASSES + c];
            // boxes with score <= SCORE_THR can never be kept and never suppress
            sc[k] = (s > SCORE_THR) ? s : -1.0f;
        } else {
            bx1[k] = 0.f; by1[k] = 0.f; bx2[k] = 0.f; by2[k] = 0.f; bar[k] = 0.f;
            sc[k] = -1.0f;
        }
    }

    __shared__ float wscore[NWAVES];
    __shared__ int   widx[NWAVES];

    for (int count = 0; count < MAX_BOXES; ++count) {
        // per-thread argmax (stable: lowest index wins on ties; k ascending -> j ascending)
        float bs = -1.0f;
        int   bi = N_ANCHORS;
        #pragma unroll
        for (int k = 0; k < PER_THREAD; ++k) {
            int j = tid + k * BLOCK;
            if (sc[k] > bs || (sc[k] == bs && j < bi)) { bs = sc[k]; bi = j; }
        }
        // wave (64-lane) reduce
        #pragma unroll
        for (int off = 32; off >= 1; off >>= 1) {
            float os = __shfl_down(bs, off);
            int   oi = __shfl_down(bi, off);
            if (os > bs || (os == bs && oi < bi)) { bs = os; bi = oi; }
        }
        const int wave = tid >> 6;
        if ((tid & 63) == 0) { wscore[wave] = bs; widx[wave] = bi; }
        __syncthreads();
        // final reduce done redundantly by every thread (uniform result, no bcast sync)
        float fs = wscore[0];
        int   fi = widx[0];
        #pragma unroll
        for (int w = 1; w < NWAVES; ++w) {
            float os = wscore[w];
            int   oi = widx[w];
            if (os > fs || (os == fs && oi < fi)) { fs = os; fi = oi; }
        }
        __syncthreads();   // wscore/widx safe to overwrite next iteration

        if (fs < 0.0f) break;   // no valid unsuppressed box remains (uniform)

        // best box via uniform-address load (scalarized, L1-resident)
        float X1 = boxes[fi * 4 + 0];
        float Y1 = boxes[fi * 4 + 1];
        float X2 = boxes[fi * 4 + 2];
        float Y2 = boxes[fi * 4 + 3];
        float AR = (X2 - X1) * (Y2 - Y1);

        if (tid == 0) out[fi * OUT_COLS + 4 + c] = fs;   // record keep

        // suppress IoU > 0.5 (self has IoU 1 -> masked from reselection)
        #pragma unroll
        for (int k = 0; k < PER_THREAD; ++k) {
            if (sc[k] > 0.0f) {
                float iw = fminf(X2, bx2[k]) - fmaxf(X1, bx1[k]);
                float ih = fminf(Y2, by2[k]) - fmaxf(Y1, by1[k]);
                iw = fmaxf(iw, 0.0f);
                ih = fmaxf(ih, 0.0f);
                float inter = iw * ih;
                float uni   = fmaxf(AR + bar[k] - inter, 1e-8f);
                if (inter > NMS_THR * uni) sc[k] = -1.0f;  // iou > 0.5
            }
        }
    }
}

// Write box columns, zero score columns (d_out is poisoned before every call).
__global__ void init_out(const float* __restrict__ boxes, float* __restrict__ out) {
    int i = blockIdx.x * blockDim.x + threadIdx.x;
    if (i < N_ANCHORS * OUT_COLS) {
        int row = i / OUT_COLS;
        int col = i - row * OUT_COLS;
        out[i] = (col < 4) ? boxes[row * 4 + col] : 0.0f;
    }
}

extern "C" void kernel_launch(void* const* d_in, const int* in_sizes, int n_in,
                              void* d_out, int out_size, void* d_ws, size_t ws_size,
                              hipStream_t stream) {
    const float* boxes = (const float*)d_in[0];
    const float* cls   = (const float*)d_in[1];
    float* out = (float*)d_out;

    const int total = N_ANCHORS * OUT_COLS;
    init_out<<<(total + 255) / 256, 256, 0, stream>>>(boxes, out);
    nms_kernel<<<N_CLASSES, BLOCK, 0, stream>>>(boxes, cls, out);
}

// Round 2
// 345.610 us; speedup vs baseline: 2.2810x; 2.2810x over previous
//
#include <hip/hip_runtime.h>

#define N_ANCHORS 5000
#define N_CLASSES 80
#define OUT_COLS  (N_CLASSES + 4)   // 84
#define MAX_BOXES 300
#define NMS_THR   0.5f
#define SCORE_THR 0.05f

#define NWORDS    80                 // ceil(5000/64)=79, pad to 80
#define NCHUNK    79                 // ceil(5000/64) chunks of 64 sorted entries
#define SORT_N    8192               // next pow2 >= 5000
#define SORT_PAD  (NCHUNK * 64)      // 5056 entries stored per class

// ---------- helpers ----------
__device__ inline unsigned long long shfl_u64(unsigned long long v, int src) {
    int lo = __shfl((int)(unsigned)(v & 0xFFFFFFFFull), src);
    int hi = __shfl((int)(unsigned)(v >> 32), src);
    return ((unsigned long long)(unsigned)hi << 32) | (unsigned)lo;
}

// ---------- 1) output init: box columns + zeroed score columns ----------
__global__ void init_out(const float* __restrict__ boxes, float* __restrict__ out) {
    int i = blockIdx.x * blockDim.x + threadIdx.x;
    if (i < N_ANCHORS * OUT_COLS) {
        int row = i / OUT_COLS;
        int col = i - row * OUT_COLS;
        out[i] = (col < 4) ? boxes[row * 4 + col] : 0.0f;
    }
}

// ---------- 2) IoU>0.5 bitmask, shared across classes ----------
// grid: (79 i-chunks, 80 words), 64 threads. Thread t: box i = bx*64+t,
// computes word w = by (bits for j = w*64 .. w*64+63).
__global__ __launch_bounds__(64) void build_mask(const float* __restrict__ boxes,
                                                 unsigned long long* __restrict__ mask) {
    const int t = threadIdx.x;
    const int i = blockIdx.x * 64 + t;
    const int w = blockIdx.y;

    __shared__ float jx1[64], jy1[64], jx2[64], jy2[64], jar[64];
    {
        int j = w * 64 + t;
        if (j < N_ANCHORS) {
            float a = boxes[j * 4 + 0], b = boxes[j * 4 + 1];
            float c = boxes[j * 4 + 2], d = boxes[j * 4 + 3];
            jx1[t] = a; jy1[t] = b; jx2[t] = c; jy2[t] = d;
            jar[t] = (c - a) * (d - b);
        } else {
            // far-away degenerate box -> IoU 0 with everything
            jx1[t] = 3.0e8f; jy1[t] = 3.0e8f; jx2[t] = 3.0e8f; jy2[t] = 3.0e8f;
            jar[t] = 0.0f;
        }
    }
    __syncthreads();

    if (i >= N_ANCHORS) return;
    float x1 = boxes[i * 4 + 0], y1 = boxes[i * 4 + 1];
    float x2 = boxes[i * 4 + 2], y2 = boxes[i * 4 + 3];
    float ar = (x2 - x1) * (y2 - y1);

    unsigned long long bits = 0ull;
    #pragma unroll
    for (int b = 0; b < 64; ++b) {
        float iw = fminf(x2, jx2[b]) - fmaxf(x1, jx1[b]);
        float ih = fminf(y2, jy2[b]) - fmaxf(y1, jy1[b]);
        iw = fmaxf(iw, 0.0f); ih = fmaxf(ih, 0.0f);
        float inter = iw * ih;
        float uni = fmaxf(ar + jar[b] - inter, 1e-8f);
        if (inter > NMS_THR * uni) bits |= (1ull << b);
    }
    mask[(size_t)i * NWORDS + w] = bits;
}

// ---------- 3) per-class bitonic sort (descending score, stable by idx) ----------
// key = (score_bits << 32) | ~idx ; invalid/padding = 0
__global__ __launch_bounds__(512) void sort_cls(const float* __restrict__ cls,
                                                unsigned long long* __restrict__ sorted) {
    __shared__ unsigned long long a[SORT_N];   // 64 KiB
    const int c = blockIdx.x;
    const int t = threadIdx.x;

    for (int j = t; j < SORT_N; j += 512) {
        unsigned long long key = 0ull;
        if (j < N_ANCHORS) {
            float s = cls[j * N_CLASSES + c];
            if (s > SCORE_THR)
                key = ((unsigned long long)__float_as_uint(s) << 32) | (unsigned)(~(unsigned)j);
        }
        a[j] = key;
    }
    __syncthreads();

    for (int k = 2; k <= SORT_N; k <<= 1) {
        for (int j2 = k >> 1; j2 > 0; j2 >>= 1) {
            for (int p = t; p < SORT_N / 2; p += 512) {
                int i  = 2 * p - (p & (j2 - 1));
                int ix = i + j2;                    // i ^ j2 (bit j2 of i is 0)
                unsigned long long ai = a[i], aj = a[ix];
                bool descSeg = ((i & k) == 0);      // overall descending sort
                bool swap = descSeg ? (ai < aj) : (ai > aj);
                if (swap) { a[i] = aj; a[ix] = ai; }
            }
            __syncthreads();
        }
    }

    for (int v = t; v < SORT_PAD; v += 512)
        sorted[(size_t)c * SORT_PAD + v] = a[v];
}

// ---------- 4) per-class serial scan with distributed bitmap ----------
// one wave per class; lane l holds suppressed word l (S0) and word 64+l (S1, l<16)
__global__ __launch_bounds__(64) void scan_nms(const unsigned long long* __restrict__ sorted,
                                               const unsigned long long* __restrict__ mask,
                                               const float* __restrict__ cls,
                                               float* __restrict__ out) {
    const int c = blockIdx.x;
    const int lane = threadIdx.x;

    unsigned long long S0 = 0ull, S1 = 0ull;
    int kept = 0;

    for (int chunk = 0; chunk < NCHUNK; ++chunk) {
        unsigned long long ent = sorted[(size_t)c * SORT_PAD + chunk * 64 + lane];
        unsigned sbits = (unsigned)(ent >> 32);
        bool validL = (sbits != 0u);
        int j = (int)(~(unsigned)(ent & 0xFFFFFFFFull));   // recover idx
        float sc = __uint_as_float(sbits);
        int W = j >> 6;
        int b = j & 63;

        unsigned long long validMask = __ballot(validL);
        if (validMask == 0ull) break;

        unsigned long long remaining = validMask;
        while (remaining) {
            // parallel aliveness check vs current bitmap
            unsigned long long w0 = shfl_u64(S0, W & 63);
            unsigned long long w1 = shfl_u64(S1, W & 63);
            unsigned long long word = (W < 64) ? w0 : w1;
            bool alive = validL && !((word >> b) & 1ull);
            unsigned long long amask = __ballot(alive) & remaining;
            if (amask == 0ull) break;

            int pos = __ffsll((long long)amask) - 1;
            int jk = __shfl(j, pos);
            float sk = __shfl(sc, pos);

            // keep box jk: OR its suppression row into the bitmap
            const unsigned long long* row = mask + (size_t)jk * NWORDS;
            S0 |= row[lane];
            if (lane < 16) S1 |= row[64 + lane];
            if (lane == 0) out[jk * OUT_COLS + 4 + c] = sk;
            ++kept;
            if (kept == MAX_BOXES) return;

            // drop pos and everything before it; survivors re-checked vs new S
            remaining = amask & ~(((unsigned long long)2 << pos) - 1ull);
        }

        // chunk contained padding/invalid tail -> list exhausted
        if (__popcll(validMask) < 64) break;
    }
}

extern "C" void kernel_launch(void* const* d_in, const int* in_sizes, int n_in,
                              void* d_out, int out_size, void* d_ws, size_t ws_size,
                              hipStream_t stream) {
    const float* boxes = (const float*)d_in[0];
    const float* cls   = (const float*)d_in[1];
    float* out = (float*)d_out;

    unsigned long long* mask   = (unsigned long long*)d_ws;                       // 5000*80*8 = 3.2 MB
    unsigned long long* sorted = (unsigned long long*)((char*)d_ws + (size_t)N_ANCHORS * NWORDS * 8);
                                                                                  // 80*5056*8 ≈ 3.24 MB

    const int total = N_ANCHORS * OUT_COLS;
    init_out<<<(total + 255) / 256, 256, 0, stream>>>(boxes, out);

    dim3 mg((N_ANCHORS + 63) / 64, NWORDS);
    build_mask<<<mg, 64, 0, stream>>>(boxes, mask);

    sort_cls<<<N_CLASSES, 512, 0, stream>>>(cls, sorted);

    scan_nms<<<N_CLASSES, 64, 0, stream>>>(sorted, mask, cls, out);
}

// Round 3
// 229.097 us; speedup vs baseline: 3.4411x; 1.5086x over previous
//
#include <hip/hip_runtime.h>

#define N_ANCHORS 5000
#define N_CLASSES 80
#define OUT_COLS  (N_CLASSES + 4)   // 84
#define MAX_BOXES 300
#define NMS_THR   0.5f
#define SCORE_THR 0.05f

#define NWORDS    80                 // ceil(5000/64)=79, pad to 80
#define NCHUNK    79                 // chunks of 64 sorted entries
#define SORT_PAD  (NCHUNK * 64)      // 5056 slots per class
#define NB        4096               // score buckets per class

typedef unsigned long long u64;
typedef unsigned int u32;

// ---------- 1) output init ----------
__global__ void init_out(const float* __restrict__ boxes, float* __restrict__ out) {
    int i = blockIdx.x * blockDim.x + threadIdx.x;
    if (i < N_ANCHORS * OUT_COLS) {
        int row = i / OUT_COLS;
        int col = i - row * OUT_COLS;
        out[i] = (col < 4) ? boxes[row * 4 + col] : 0.0f;
    }
}

// ---------- 2) IoU>0.5 bitmask over raw anchor indices ----------
__global__ __launch_bounds__(64) void build_mask(const float* __restrict__ boxes,
                                                 u64* __restrict__ mask) {
    const int t = threadIdx.x;
    const int i = blockIdx.x * 64 + t;
    const int w = blockIdx.y;

    __shared__ float jx1[64], jy1[64], jx2[64], jy2[64], jar[64];
    {
        int j = w * 64 + t;
        if (j < N_ANCHORS) {
            float a = boxes[j * 4 + 0], b = boxes[j * 4 + 1];
            float c = boxes[j * 4 + 2], d = boxes[j * 4 + 3];
            jx1[t] = a; jy1[t] = b; jx2[t] = c; jy2[t] = d;
            jar[t] = (c - a) * (d - b);
        } else {
            jx1[t] = 3.0e8f; jy1[t] = 3.0e8f; jx2[t] = 3.0e8f; jy2[t] = 3.0e8f;
            jar[t] = 0.0f;
        }
    }
    __syncthreads();

    if (i >= N_ANCHORS) return;
    float x1 = boxes[i * 4 + 0], y1 = boxes[i * 4 + 1];
    float x2 = boxes[i * 4 + 2], y2 = boxes[i * 4 + 3];
    float ar = (x2 - x1) * (y2 - y1);

    u64 bits = 0ull;
    #pragma unroll
    for (int b = 0; b < 64; ++b) {
        float iw = fmaxf(fminf(x2, jx2[b]) - fmaxf(x1, jx1[b]), 0.0f);
        float ih = fmaxf(fminf(y2, jy2[b]) - fmaxf(y1, jy1[b]), 0.0f);
        float inter = iw * ih;
        float uni = fmaxf(ar + jar[b] - inter, 1e-8f);
        if (inter > NMS_THR * uni) bits |= (1ull << b);
    }
    mask[(size_t)i * NWORDS + w] = bits;
}

// ---------- bucket map: monotone in score (exactness never depends on it) ----------
__device__ inline int bucket_of(float s) {
    float u = sqrtf(s);                       // scores are u^2 of uniform u -> ~uniform buckets
    int b = (int)((u - 0.2236f) * 5275.0f);
    return min(max(b, 0), NB - 1);
}

// ---------- 3a) per-class bucket histogram + exclusive prefix ----------
// gStart layout: [class][NB+1], gStart[c][b]=start of bucket b, gStart[c][NB]=count
__global__ __launch_bounds__(256) void bucket_hist(const float* __restrict__ cls,
                                                   u32* __restrict__ gStart) {
    const int c = blockIdx.x;
    const int t = threadIdx.x;
    __shared__ u32 hist[NB];
    __shared__ u32 wtot[4];

    for (int b = t; b < NB; b += 256) hist[b] = 0;
    __syncthreads();

    for (int j = t; j < N_ANCHORS; j += 256) {
        float s = cls[j * N_CLASSES + c];
        if (s > SCORE_THR) atomicAdd(&hist[bucket_of(s)], 1u);
    }
    __syncthreads();

    // block inclusive scan: each thread owns 16 consecutive buckets
    const int base = t * 16;
    u32 vals[16];
    u32 run = 0;
    #pragma unroll
    for (int k = 0; k < 16; ++k) { run += hist[base + k]; vals[k] = run; }

    // wave inclusive scan of per-thread sums
    u32 x = run;
    const int lane = t & 63;
    #pragma unroll
    for (int off = 1; off < 64; off <<= 1) {
        u32 y = __shfl_up(x, off);
        if (lane >= off) x += y;
    }
    if (lane == 63) wtot[t >> 6] = x;
    __syncthreads();
    u32 woff = 0;
    for (int w = 0; w < (t >> 6); ++w) woff += wtot[w];
    u32 exbase = woff + x - run;   // exclusive prefix for this thread's 16 buckets

    u32* gs = gStart + (size_t)c * (NB + 1);
    #pragma unroll
    for (int k = 0; k < 16; ++k) gs[1 + base + k] = exbase + vals[k];  // inclusive -> start of b+1
    if (t == 0) gs[0] = 0;
}

// ---------- 3b) scatter keys into bucket slots (order within bucket arbitrary) ----------
__global__ __launch_bounds__(256) void bucket_scatter(const float* __restrict__ cls,
                                                      const u32* __restrict__ gStart,
                                                      u64* __restrict__ keys) {
    const int c = blockIdx.x;
    const int t = threadIdx.x;
    __shared__ u32 scur[NB];
    const u32* gs = gStart + (size_t)c * (NB + 1);

    for (int b = t; b < NB; b += 256) scur[b] = gs[b];
    __syncthreads();

    u64* kc = keys + (size_t)c * SORT_PAD;
    for (int j = t; j < N_ANCHORS; j += 256) {
        float s = cls[j * N_CLASSES + c];
        if (s > SCORE_THR) {
            u32 pos = atomicAdd(&scur[bucket_of(s)], 1u);
            kc[pos] = ((u64)__float_as_uint(s) << 32) | (u32)(~(u32)j);
        }
    }
    // zero tail (d_ws is poisoned)
    u32 count = gs[NB];
    for (int v = (int)count + t; v < SORT_PAD; v += 256) kc[v] = 0ull;
}

// ---------- 3c) exact sort within each bucket + gather boxes into sorted order ----------
__global__ __launch_bounds__(256) void bucket_sort(const u32* __restrict__ gStart,
                                                   u64* __restrict__ keys,
                                                   const float4* __restrict__ boxes4,
                                                   float4* __restrict__ boxs) {
    int g = blockIdx.x * blockDim.x + threadIdx.x;
    if (g >= N_CLASSES * NB) return;
    const int c = g >> 12;          // /NB
    const int b = g & (NB - 1);
    const u32* gs = gStart + (size_t)c * (NB + 1);
    int s0 = (int)gs[b], e = (int)gs[b + 1];
    if (s0 >= e) return;

    u64* K = keys + (size_t)c * SORT_PAD;
    // insertion sort, descending u64 key (score bits, then ~idx) — exact total order
    for (int i = s0 + 1; i < e; ++i) {
        u64 key = K[i];
        int j = i - 1;
        while (j >= s0 && K[j] < key) { K[j + 1] = K[j]; --j; }
        K[j + 1] = key;
    }
    float4* B = boxs + (size_t)c * SORT_PAD;
    for (int i = s0; i < e; ++i) {
        u32 jj = ~(u32)K[i];
        B[i] = boxes4[jj];
    }
}

// ---------- 4) per-class serial scan: direct-IoU within chunk, pipelined mask-row OR ----------
__global__ __launch_bounds__(64) void scan_nms(const u64* __restrict__ keys,
                                               const float4* __restrict__ boxs,
                                               const u64* __restrict__ mask,
                                               float* __restrict__ out) {
    const int c = blockIdx.x;
    const int lane = threadIdx.x;

    __shared__ u64 BM[NWORDS];     // suppressed bitmap over raw anchor indices
    BM[lane] = 0ull;
    if (lane < NWORDS - 64) BM[64 + lane] = 0ull;

    const size_t base = (size_t)c * SORT_PAD;
    u64 p0 = 0ull, p1 = 0ull;      // pending mask row of the most recent keep
    int kept = 0;

    u64 key = keys[base + lane];   // chunk 0 (prefetched ahead of loop)
    float4 bx = boxs[base + lane];

    for (int chunk = 0; chunk < NCHUNK; ++chunk) {
        // issue next chunk's loads now; consumed at loop end
        u64 keyN = 0ull;
        float4 bxN = make_float4(0.f, 0.f, 0.f, 0.f);
        if (chunk + 1 < NCHUNK) {
            keyN = keys[base + (size_t)(chunk + 1) * 64 + lane];
            bxN  = boxs[base + (size_t)(chunk + 1) * 64 + lane];
        }

        bool valid = (key != 0ull);
        u64 vm = __ballot(valid);
        if (vm == 0ull) break;

        u32 j = valid ? ~(u32)key : 0u;
        int W = (int)(j >> 6);
        int bpos = (int)(j & 63u);
        float sc = __uint_as_float((u32)(key >> 32));
        float ar = (bx.z - bx.x) * (bx.w - bx.y);

        // flush pending row from previous chunk's last keep (lane owns its words: no races)
        BM[lane] |= p0;
        if (lane < NWORDS - 64) BM[64 + lane] |= p1;
        p0 = 0ull; p1 = 0ull;

        // cross-chunk suppression via bitmap
        u64 word = BM[W];
        bool alive = valid && !((word >> bpos) & 1ull);
        u64 rem = __ballot(alive);

        while (rem) {
            int pos = __ffsll((long long)rem) - 1;
            float kx1 = __shfl(bx.x, pos);
            float ky1 = __shfl(bx.y, pos);
            float kx2 = __shfl(bx.z, pos);
            float ky2 = __shfl(bx.w, pos);
            float ks  = __shfl(sc, pos);
            u32   jk  = (u32)__shfl((int)j, pos);

            if (lane == 0) out[jk * OUT_COLS + 4 + c] = ks;

            // flush previous pending row, then issue this keep's row load (off critical path)
            BM[lane] |= p0;
            if (lane < NWORDS - 64) BM[64 + lane] |= p1;
            const u64* row = mask + (size_t)jk * NWORDS;
            p0 = row[lane];
            p1 = (lane < NWORDS - 64) ? row[64 + lane] : 0ull;

            ++kept;
            if (kept == MAX_BOXES) return;

            // within-chunk suppression by direct IoU (kills lane pos itself: IoU=1)
            float AR = (kx2 - kx1) * (ky2 - ky1);
            float iw = fmaxf(fminf(kx2, bx.z) - fmaxf(kx1, bx.x), 0.0f);
            float ih = fmaxf(fminf(ky2, bx.w) - fmaxf(ky1, bx.y), 0.0f);
            float inter = iw * ih;
            float uni = fmaxf(AR + ar - inter, 1e-8f);
            bool sup = inter > NMS_THR * uni;
            alive = alive && !sup;
            rem = __ballot(alive);
        }

        key = keyN; bx = bxN;
        if (__popcll(vm) < 64) break;   // tail reached
    }
}

extern "C" void kernel_launch(void* const* d_in, const int* in_sizes, int n_in,
                              void* d_out, int out_size, void* d_ws, size_t ws_size,
                              hipStream_t stream) {
    const float* boxes = (const float*)d_in[0];
    const float* cls   = (const float*)d_in[1];
    float* out = (float*)d_out;

    char* w = (char*)d_ws;
    u64*    mask   = (u64*)w;                 w += (size_t)N_ANCHORS * NWORDS * 8;   // 3.20 MB
    u64*    keys   = (u64*)w;                 w += (size_t)N_CLASSES * SORT_PAD * 8; // 3.24 MB
    float4* boxs   = (float4*)w;              w += (size_t)N_CLASSES * SORT_PAD * 16;// 6.47 MB
    u32*    gStart = (u32*)w;                                                        // 1.31 MB

    const int total = N_ANCHORS * OUT_COLS;
    init_out<<<(total + 255) / 256, 256, 0, stream>>>(boxes, out);

    dim3 mg((N_ANCHORS + 63) / 64, NWORDS);
    build_mask<<<mg, 64, 0, stream>>>(boxes, mask);

    bucket_hist<<<N_CLASSES, 256, 0, stream>>>(cls, gStart);
    bucket_scatter<<<N_CLASSES, 256, 0, stream>>>(cls, gStart, keys);
    bucket_sort<<<(N_CLASSES * NB + 255) / 256, 256, 0, stream>>>(gStart, keys,
                                                                  (const float4*)boxes, boxs);

    scan_nms<<<N_CLASSES, 64, 0, stream>>>(keys, boxs, mask, out);
}

// Round 4
// 204.282 us; speedup vs baseline: 3.8591x; 1.1215x over previous
//
#include <hip/hip_runtime.h>

#define N_ANCHORS 5000
#define N_CLASSES 80
#define OUT_COLS  (N_CLASSES + 4)   // 84
#define MAX_BOXES 300
#define NMS_THR   0.5f
#define SCORE_THR 0.05f

#define NWORDS    80                 // ceil(5000/64)=79, pad to 80
#define NCHUNK    79                 // chunks of 64 sorted entries
#define SORT_PAD  (NCHUNK * 64)      // 5056 slots per class
#define NB        4096               // score buckets per class
#define PT        20                 // cls entries per thread (20*256=5120>=5000)

typedef unsigned long long u64;
typedef unsigned int u32;

__device__ inline u64 shfl_u64(u64 v, int src) {
    int lo = __shfl((int)(u32)(v & 0xFFFFFFFFull), src);
    int hi = __shfl((int)(u32)(v >> 32), src);
    return ((u64)(u32)hi << 32) | (u32)lo;
}

// ---------- 1) output init ----------
__global__ void init_out(const float* __restrict__ boxes, float* __restrict__ out) {
    int i = blockIdx.x * blockDim.x + threadIdx.x;
    if (i < N_ANCHORS * OUT_COLS) {
        int row = i / OUT_COLS;
        int col = i - row * OUT_COLS;
        out[i] = (col < 4) ? boxes[row * 4 + col] : 0.0f;
    }
}

// ---------- 2) IoU>0.5 bitmask over raw anchor indices ----------
__global__ __launch_bounds__(64) void build_mask(const float* __restrict__ boxes,
                                                 u64* __restrict__ mask) {
    const int t = threadIdx.x;
    const int i = blockIdx.x * 64 + t;
    const int w = blockIdx.y;

    __shared__ float jx1[64], jy1[64], jx2[64], jy2[64], jar[64];
    {
        int j = w * 64 + t;
        if (j < N_ANCHORS) {
            float a = boxes[j * 4 + 0], b = boxes[j * 4 + 1];
            float c = boxes[j * 4 + 2], d = boxes[j * 4 + 3];
            jx1[t] = a; jy1[t] = b; jx2[t] = c; jy2[t] = d;
            jar[t] = (c - a) * (d - b);
        } else {
            jx1[t] = 3.0e8f; jy1[t] = 3.0e8f; jx2[t] = 3.0e8f; jy2[t] = 3.0e8f;
            jar[t] = 0.0f;
        }
    }
    __syncthreads();

    if (i >= N_ANCHORS) return;
    float x1 = boxes[i * 4 + 0], y1 = boxes[i * 4 + 1];
    float x2 = boxes[i * 4 + 2], y2 = boxes[i * 4 + 3];
    float ar = (x2 - x1) * (y2 - y1);

    u64 bits = 0ull;
    #pragma unroll
    for (int b = 0; b < 64; ++b) {
        float iw = fmaxf(fminf(x2, jx2[b]) - fmaxf(x1, jx1[b]), 0.0f);
        float ih = fmaxf(fminf(y2, jy2[b]) - fmaxf(y1, jy1[b]), 0.0f);
        float inter = iw * ih;
        float uni = fmaxf(ar + jar[b] - inter, 1e-8f);
        if (inter > NMS_THR * uni) bits |= (1ull << b);
    }
    mask[(size_t)i * NWORDS + w] = bits;
}

// ---------- bucket map: monotone in score (exactness never depends on it) ----------
__device__ inline int bucket_of(float s) {
    float u = sqrtf(s);
    int b = (int)((u - 0.2236f) * 5275.0f);
    return min(max(b, 0), NB - 1);
}

// ---------- 3) fused per-class sort: hist + scan + scatter + bucket-sort, LDS-resident ----------
__global__ __launch_bounds__(256) void sort_cls(const float* __restrict__ cls,
                                                u64* __restrict__ keys) {
    const int c = blockIdx.x;
    const int t = threadIdx.x;
    __shared__ u32 hist[NB];        // 16 KiB; becomes bucket cursors, then bucket ends
    __shared__ u32 wtot[4];
    __shared__ u64 lk[SORT_PAD];    // 40 KiB

    // single pass over cls, cached in registers
    u32 sb[PT];
    #pragma unroll
    for (int k = 0; k < PT; ++k) {
        int j = t + k * 256;
        sb[k] = 0u;
        if (j < N_ANCHORS) {
            float s = cls[j * N_CLASSES + c];
            if (s > SCORE_THR) sb[k] = __float_as_uint(s);
        }
    }

    for (int b = t; b < NB; b += 256) hist[b] = 0u;
    __syncthreads();

    #pragma unroll
    for (int k = 0; k < PT; ++k)
        if (sb[k]) atomicAdd(&hist[bucket_of(__uint_as_float(sb[k]))], 1u);
    __syncthreads();

    // exclusive prefix: thread owns 16 consecutive buckets
    const int base = t * 16;
    u32 vals[16];
    u32 run = 0;
    #pragma unroll
    for (int k = 0; k < 16; ++k) { run += hist[base + k]; vals[k] = run; }
    u32 x = run;
    const int lane = t & 63;
    #pragma unroll
    for (int off = 1; off < 64; off <<= 1) {
        u32 y = __shfl_up(x, off);
        if (lane >= off) x += y;
    }
    if (lane == 63) wtot[t >> 6] = x;
    __syncthreads();
    u32 woff = 0;
    for (int w = 0; w < (t >> 6); ++w) woff += wtot[w];
    const u32 exbase = woff + x - run;
    #pragma unroll
    for (int k = 0; k < 16; ++k)
        hist[base + k] = exbase + (k ? vals[k - 1] : 0u);   // start of bucket
    __syncthreads();

    // scatter into LDS slots
    #pragma unroll
    for (int k = 0; k < PT; ++k) {
        if (sb[k]) {
            int j = t + k * 256;
            u32 pos = atomicAdd(&hist[bucket_of(__uint_as_float(sb[k]))], 1u);
            lk[pos] = ((u64)sb[k] << 32) | (u32)(~(u32)j);
        }
    }
    __syncthreads();   // hist[b] is now end of bucket b (== start of b+1)

    // zero tail + insertion-sort each bucket (descending u64: score desc, idx asc)
    const int total = (int)hist[NB - 1];
    for (int v = total + t; v < SORT_PAD; v += 256) lk[v] = 0ull;
    for (int b = base; b < base + 16; ++b) {
        int s0 = b ? (int)hist[b - 1] : 0;
        int e  = (int)hist[b];
        for (int i = s0 + 1; i < e; ++i) {
            u64 key = lk[i];
            int q = i - 1;
            while (q >= s0 && lk[q] < key) { lk[q + 1] = lk[q]; --q; }
            lk[q + 1] = key;
        }
    }
    __syncthreads();

    u64* kc = keys + (size_t)c * SORT_PAD;
    for (int v = t; v < SORT_PAD; v += 256) kc[v] = lk[v];   // coalesced
}

// ---------- 4) per-class serial scan ----------
// register bitmap S0/S1 (lane owns word lane / 64+lane), depth-2 pending-row pipeline,
// within-chunk suppression by direct IoU, box coords loaded one chunk ahead.
__global__ __launch_bounds__(64) void scan_nms(const u64* __restrict__ keys,
                                               const float4* __restrict__ boxes4,
                                               const u64* __restrict__ mask,
                                               float* __restrict__ out) {
    const int c = blockIdx.x;
    const int lane = threadIdx.x;

    u64 S0 = 0ull, S1 = 0ull;                       // suppressed bitmap (registers)
    u64 q0a = 0ull, q0b = 0ull, q1a = 0ull, q1b = 0ull;  // pending rows, depth 2
    const size_t base = (size_t)c * SORT_PAD;
    int kept = 0;

    u64 key  = keys[base + lane];
    u64 keyN = keys[base + 64 + lane];
    float4 bx;
    { u32 jj = key ? ~(u32)key : 0u; bx = boxes4[jj]; }

    for (int chunk = 0; chunk < NCHUNK; ++chunk) {
        // prefetch: next chunk's boxes (from keyN), keys two ahead
        float4 bxN = make_float4(0.f, 0.f, 0.f, 0.f);
        u64 keyNN = 0ull;
        if (chunk + 1 < NCHUNK) {
            u32 jn = keyN ? ~(u32)keyN : 0u;
            bxN = boxes4[jn];
            if (chunk + 2 < NCHUNK) keyNN = keys[base + (size_t)(chunk + 2) * 64 + lane];
        }

        bool valid = (key != 0ull);
        u64 vm = __ballot(valid);
        if (vm == 0ull) break;

        // flush entire pending pipeline before consulting bitmap
        S0 |= q0a | q1a;
        S1 |= q0b | q1b;
        q0a = q0b = q1a = q1b = 0ull;

        u32 j = valid ? ~(u32)key : 0u;
        int W = (int)(j >> 6);
        int bpos = (int)(j & 63u);
        float sc = __uint_as_float((u32)(key >> 32));
        float ar = (bx.z - bx.x) * (bx.w - bx.y);

        u64 w0 = shfl_u64(S0, W & 63);
        u64 w1 = shfl_u64(S1, W & 63);
        u64 word = (W < 64) ? w0 : w1;
        bool alive = valid && !((word >> bpos) & 1ull);
        u64 rem = __ballot(alive);

        while (rem) {
            int pos = __ffsll((long long)rem) - 1;
            float kx1 = __shfl(bx.x, pos);
            float ky1 = __shfl(bx.y, pos);
            float kx2 = __shfl(bx.z, pos);
            float ky2 = __shfl(bx.w, pos);
            float ks  = __shfl(sc, pos);
            u32   jk  = (u32)__shfl((int)j, pos);

            if (lane == 0) out[jk * OUT_COLS + 4 + c] = ks;

            // rotate pending pipeline: flush oldest (issued 2 keeps ago), issue new row
            S0 |= q0a; S1 |= q0b;
            q0a = q1a; q0b = q1b;
            const u64* row = mask + (size_t)jk * NWORDS;
            q1a = row[lane];
            q1b = (lane < NWORDS - 64) ? row[64 + lane] : 0ull;

            ++kept;
            if (kept == MAX_BOXES) return;

            // within-chunk suppression by direct IoU (kills lane pos: IoU=1)
            float AR = (kx2 - kx1) * (ky2 - ky1);
            float iw = fmaxf(fminf(kx2, bx.z) - fmaxf(kx1, bx.x), 0.0f);
            float ih = fmaxf(fminf(ky2, bx.w) - fmaxf(ky1, bx.y), 0.0f);
            float inter = iw * ih;
            float uni = fmaxf(AR + ar - inter, 1e-8f);
            alive = alive && !(inter > NMS_THR * uni);
            rem = __ballot(alive);
        }

        key = keyN; keyN = keyNN; bx = bxN;
        if (__popcll(vm) < 64) break;   // sorted+packed: tail reached
    }
}

extern "C" void kernel_launch(void* const* d_in, const int* in_sizes, int n_in,
                              void* d_out, int out_size, void* d_ws, size_t ws_size,
                              hipStream_t stream) {
    const float* boxes = (const float*)d_in[0];
    const float* cls   = (const float*)d_in[1];
    float* out = (float*)d_out;

    char* w = (char*)d_ws;
    u64* mask = (u64*)w;   w += (size_t)N_ANCHORS * NWORDS * 8;    // 3.20 MB
    u64* keys = (u64*)w;                                           // 3.24 MB

    const int total = N_ANCHORS * OUT_COLS;
    init_out<<<(total + 255) / 256, 256, 0, stream>>>(boxes, out);

    dim3 mg((N_ANCHORS + 63) / 64, NWORDS);
    build_mask<<<mg, 64, 0, stream>>>(boxes, mask);

    sort_cls<<<N_CLASSES, 256, 0, stream>>>(cls, keys);

    scan_nms<<<N_CLASSES, 64, 0, stream>>>(keys, (const float4*)boxes, mask, out);
}

// Round 5
// 184.819 us; speedup vs baseline: 4.2655x; 1.1053x over previous
//
#include <hip/hip_runtime.h>

#define N_ANCHORS 5000
#define N_CLASSES 80
#define OUT_COLS  (N_CLASSES + 4)   // 84
#define MAX_BOXES 300
#define NMS_THR   0.5f
#define SCORE_THR 0.05f

#define NWORDS    80                 // ceil(5000/64)=79, pad to 80
#define NCHUNK    79                 // chunks of 64 sorted entries
#define SORT_PAD  (NCHUNK * 64)      // 5056 slots per class
#define NB        4096               // score buckets per class
#define PT        20                 // cls entries per thread (5*float4)
#define GRP       16                 // rows OR'd per group in scan flush

typedef unsigned long long u64;
typedef unsigned int u32;

__device__ inline u64 shfl_u64(u64 v, int src) {
    int lo = __shfl((int)(u32)(v & 0xFFFFFFFFull), src);
    int hi = __shfl((int)(u32)(v >> 32), src);
    return ((u64)(u32)hi << 32) | (u32)lo;
}
__device__ inline float readlane_f(float v, int lane) {
    return __int_as_float(__builtin_amdgcn_readlane(__float_as_int(v), lane));
}

// ---------- 1) output init ----------
__global__ void init_out(const float* __restrict__ boxes, float* __restrict__ out) {
    int i = blockIdx.x * blockDim.x + threadIdx.x;
    if (i < N_ANCHORS * OUT_COLS) {
        int row = i / OUT_COLS;
        int col = i - row * OUT_COLS;
        out[i] = (col < 4) ? boxes[row * 4 + col] : 0.0f;
    }
}

// ---------- 2) IoU>0.5 bitmask over raw anchor indices ----------
__global__ __launch_bounds__(64) void build_mask(const float4* __restrict__ boxes4,
                                                 u64* __restrict__ mask) {
    const int t = threadIdx.x;
    const int i = blockIdx.x * 64 + t;
    const int w = blockIdx.y;

    __shared__ float4 jb[64];
    __shared__ float  ja[64];
    {
        int j = w * 64 + t;
        if (j < N_ANCHORS) {
            float4 v = boxes4[j];
            jb[t] = v;
            ja[t] = (v.z - v.x) * (v.w - v.y);
        } else {
            jb[t] = make_float4(3.0e8f, 3.0e8f, 3.0e8f, 3.0e8f);
            ja[t] = 0.0f;
        }
    }
    __syncthreads();

    if (i >= N_ANCHORS) return;
    float4 bi = boxes4[i];
    float ar = (bi.z - bi.x) * (bi.w - bi.y);

    u64 bits = 0ull;
    #pragma unroll
    for (int b = 0; b < 64; ++b) {
        float4 bj = jb[b];
        float iw = fmaxf(fminf(bi.z, bj.z) - fmaxf(bi.x, bj.x), 0.0f);
        float ih = fmaxf(fminf(bi.w, bj.w) - fmaxf(bi.y, bj.y), 0.0f);
        float inter = iw * ih;
        float uni = fmaxf(ar + ja[b] - inter, 1e-8f);
        if (inter > NMS_THR * uni) bits |= (1ull << b);
    }
    mask[(size_t)i * NWORDS + w] = bits;
}

// ---------- 3a) tiled transpose: cls[j][c] -> clsT[c][j] (coalesced both ways) ----------
__global__ __launch_bounds__(256) void transpose_cls(const float* __restrict__ cls,
                                                     float* __restrict__ clsT) {
    __shared__ float tile[32][33];
    const int j0 = blockIdx.x * 32;
    const int c0 = blockIdx.y * 32;
    const int tx = threadIdx.x & 31;
    const int ty = threadIdx.x >> 5;   // 0..7

    #pragma unroll
    for (int r = 0; r < 32; r += 8) {
        int j = j0 + ty + r, c = c0 + tx;
        tile[ty + r][tx] = (j < N_ANCHORS && c < N_CLASSES) ? cls[j * N_CLASSES + c] : 0.0f;
    }
    __syncthreads();
    #pragma unroll
    for (int r = 0; r < 32; r += 8) {
        int c = c0 + ty + r, j = j0 + tx;
        if (c < N_CLASSES && j < N_ANCHORS) clsT[(size_t)c * N_ANCHORS + j] = tile[tx][ty + r];
    }
}

// ---------- bucket map: monotone in score (exactness never depends on it) ----------
__device__ inline int bucket_of(float s) {
    float u = sqrtf(s);
    int b = (int)((u - 0.2236f) * 5275.0f);
    return min(max(b, 0), NB - 1);
}

// ---------- 3b) fused per-class sort, coalesced float4 reads of clsT ----------
__global__ __launch_bounds__(256) void sort_cls(const float* __restrict__ clsT,
                                                u64* __restrict__ keys) {
    const int c = blockIdx.x;
    const int t = threadIdx.x;
    __shared__ u32 hist[NB];        // 16 KiB; cursors, then bucket ends
    __shared__ u32 wtot[4];
    __shared__ u64 lk[SORT_PAD];    // 40 KiB

    // coalesced single pass: thread t covers j = k*1024 + 4t + r
    const float4* cp4 = (const float4*)(clsT + (size_t)c * N_ANCHORS);
    u32 sb[PT];
    #pragma unroll
    for (int k = 0; k < 5; ++k) {
        int j = k * 1024 + t * 4;
        float4 v = make_float4(0.f, 0.f, 0.f, 0.f);
        if (j < N_ANCHORS) v = cp4[(k * 1024) / 4 + t];   // 5000%4==0: full vectors only
        sb[k * 4 + 0] = (v.x > SCORE_THR) ? __float_as_uint(v.x) : 0u;
        sb[k * 4 + 1] = (v.y > SCORE_THR) ? __float_as_uint(v.y) : 0u;
        sb[k * 4 + 2] = (v.z > SCORE_THR) ? __float_as_uint(v.z) : 0u;
        sb[k * 4 + 3] = (v.w > SCORE_THR) ? __float_as_uint(v.w) : 0u;
    }

    for (int b = t; b < NB; b += 256) hist[b] = 0u;
    __syncthreads();

    #pragma unroll
    for (int m = 0; m < PT; ++m)
        if (sb[m]) atomicAdd(&hist[bucket_of(__uint_as_float(sb[m]))], 1u);
    __syncthreads();

    // exclusive prefix: thread owns 16 consecutive buckets
    const int base = t * 16;
    u32 vals[16];
    u32 run = 0;
    #pragma unroll
    for (int k = 0; k < 16; ++k) { run += hist[base + k]; vals[k] = run; }
    u32 x = run;
    const int lane = t & 63;
    #pragma unroll
    for (int off = 1; off < 64; off <<= 1) {
        u32 y = __shfl_up(x, off);
        if (lane >= off) x += y;
    }
    if (lane == 63) wtot[t >> 6] = x;
    __syncthreads();
    u32 woff = 0;
    for (int w = 0; w < (t >> 6); ++w) woff += wtot[w];
    const u32 exbase = woff + x - run;
    #pragma unroll
    for (int k = 0; k < 16; ++k)
        hist[base + k] = exbase + (k ? vals[k - 1] : 0u);
    __syncthreads();

    // scatter into LDS slots
    #pragma unroll
    for (int m = 0; m < PT; ++m) {
        if (sb[m]) {
            int j = (m >> 2) * 1024 + t * 4 + (m & 3);
            u32 pos = atomicAdd(&hist[bucket_of(__uint_as_float(sb[m]))], 1u);
            lk[pos] = ((u64)sb[m] << 32) | (u32)(~(u32)j);
        }
    }
    __syncthreads();   // hist[b] now end of bucket b

    const int total = (int)hist[NB - 1];
    for (int v = total + t; v < SORT_PAD; v += 256) lk[v] = 0ull;
    for (int b = base; b < base + 16; ++b) {
        int s0 = b ? (int)hist[b - 1] : 0;
        int e  = (int)hist[b];
        for (int i = s0 + 1; i < e; ++i) {
            u64 key = lk[i];
            int q = i - 1;
            while (q >= s0 && lk[q] < key) { lk[q + 1] = lk[q]; --q; }
            lk[q + 1] = key;
        }
    }
    __syncthreads();

    u64* kc = keys + (size_t)c * SORT_PAD;
    for (int v = t; v < SORT_PAD; v += 256) kc[v] = lk[v];
}

// ---------- 4) per-class serial scan ----------
// Keep loop: pure readlane+IoU+ballot (no memory ops on the chain).
// Mask rows OR'd into register bitmap at chunk end, 16 rows per group in flight.
__global__ __launch_bounds__(64) void scan_nms(const u64* __restrict__ keys,
                                               const float4* __restrict__ boxes4,
                                               const u64* __restrict__ mask,
                                               float* __restrict__ out) {
    const int c = blockIdx.x;
    const int lane = threadIdx.x;

    u64 S0 = 0ull, S1 = 0ull;          // suppressed bitmap: lane owns word lane / 64+lane
    const size_t base = (size_t)c * SORT_PAD;
    int kept = 0;

    u64 key  = keys[base + lane];
    u64 keyN = keys[base + 64 + lane];
    float4 bx;
    { u32 jj = key ? ~(u32)key : 0u; bx = boxes4[jj]; }

    for (int chunk = 0; chunk < NCHUNK; ++chunk) {
        // prefetch next chunk
        float4 bxN = make_float4(0.f, 0.f, 0.f, 0.f);
        u64 keyNN = 0ull;
        if (chunk + 1 < NCHUNK) {
            u32 jn = keyN ? ~(u32)keyN : 0u;
            bxN = boxes4[jn];
            if (chunk + 2 < NCHUNK) keyNN = keys[base + (size_t)(chunk + 2) * 64 + lane];
        }

        bool valid = (key != 0ull);
        u64 vm = __ballot(valid);
        if (vm == 0ull) break;

        u32 j = valid ? ~(u32)key : 0u;
        int W = (int)(j >> 6);
        int bpos = (int)(j & 63u);
        float sc = __uint_as_float((u32)(key >> 32));
        float ar = (bx.z - bx.x) * (bx.w - bx.y);

        // cross-chunk suppression via register bitmap
        u64 w0 = shfl_u64(S0, W & 63);
        u64 w1 = shfl_u64(S1, W & 63);
        u64 word = (W < 64) ? w0 : w1;
        bool alive = valid && !((word >> bpos) & 1ull);
        u64 rem = __ballot(alive);

        // ---- keep loop: no memory ops ----
        u64 km = 0ull;
        bool capped = false;
        while (rem) {
            int pos = __ffsll(rem) - 1;
            km |= (1ull << pos);
            ++kept;
            if (kept == MAX_BOXES) { capped = true; break; }
            float kx1 = readlane_f(bx.x, pos);
            float ky1 = readlane_f(bx.y, pos);
            float kx2 = readlane_f(bx.z, pos);
            float ky2 = readlane_f(bx.w, pos);
            float AR = (kx2 - kx1) * (ky2 - ky1);
            float iw = fmaxf(fminf(kx2, bx.z) - fmaxf(kx1, bx.x), 0.0f);
            float ih = fmaxf(fminf(ky2, bx.w) - fmaxf(ky1, bx.y), 0.0f);
            float inter = iw * ih;
            float uni = fmaxf(AR + ar - inter, 1e-8f);
            alive = alive && !(inter > NMS_THR * uni);   // kills pos itself (IoU=1)
            rem = __ballot(alive);
        }

        // kept lanes store their own score (one predicated scattered store per chunk)
        if ((km >> lane) & 1ull) out[(size_t)j * OUT_COLS + 4 + c] = sc;
        if (capped) return;

        // ---- OR kept rows into bitmap, GRP rows in flight per group ----
        u64 t = km;
        while (t) {
            u32 idx[GRP]; u64 mv[GRP];
            #pragma unroll
            for (int q = 0; q < GRP; ++q) {
                bool have = (t != 0ull);
                int pp = have ? (__ffsll(t) - 1) : 0;
                idx[q] = (u32)__builtin_amdgcn_readlane((int)j, pp);
                mv[q] = have ? ~0ull : 0ull;
                if (have) t &= t - 1;
            }
            u64 a[GRP], b[GRP];
            #pragma unroll
            for (int q = 0; q < GRP; ++q) {
                const u64* row = mask + (size_t)(mv[q] ? idx[q] : 0u) * NWORDS;
                a[q] = row[lane];
                b[q] = (lane < NWORDS - 64) ? row[64 + lane] : 0ull;
            }
            #pragma unroll
            for (int q = 0; q < GRP; ++q) { S0 |= a[q] & mv[q]; S1 |= b[q] & mv[q]; }
        }

        key = keyN; keyN = keyNN; bx = bxN;
        if (__popcll(vm) < 64) break;   // sorted+packed: tail reached
    }
}

extern "C" void kernel_launch(void* const* d_in, const int* in_sizes, int n_in,
                              void* d_out, int out_size, void* d_ws, size_t ws_size,
                              hipStream_t stream) {
    const float* boxes = (const float*)d_in[0];
    const float* cls   = (const float*)d_in[1];
    float* out = (float*)d_out;

    char* w = (char*)d_ws;
    u64*   mask = (u64*)w;    w += (size_t)N_ANCHORS * NWORDS * 8;     // 3.20 MB
    u64*   keys = (u64*)w;    w += (size_t)N_CLASSES * SORT_PAD * 8;   // 3.24 MB
    float* clsT = (float*)w;                                           // 1.60 MB

    const int total = N_ANCHORS * OUT_COLS;
    init_out<<<(total + 255) / 256, 256, 0, stream>>>(boxes, out);

    dim3 mg((N_ANCHORS + 63) / 64, NWORDS);
    build_mask<<<mg, 64, 0, stream>>>((const float4*)boxes, mask);

    dim3 tg((N_ANCHORS + 31) / 32, (N_CLASSES + 31) / 32);
    transpose_cls<<<tg, 256, 0, stream>>>(cls, clsT);

    sort_cls<<<N_CLASSES, 256, 0, stream>>>(clsT, keys);

    scan_nms<<<N_CLASSES, 64, 0, stream>>>(keys, (const float4*)boxes, mask, out);
}

// Round 6
// 167.978 us; speedup vs baseline: 4.6931x; 1.1003x over previous
//
#include <hip/hip_runtime.h>

#define N_ANCHORS 5000
#define N_CLASSES 80
#define OUT_COLS  (N_CLASSES + 4)   // 84
#define MAX_BOXES 300
#define SCORE_THR 0.05f

#define NWORDS    80                 // ceil(5000/64)=79, pad to 80
#define NCHUNK    79                 // chunks of 64 sorted entries
#define SORT_PAD  (NCHUNK * 64)      // 5056 slots per class
#define NB        4096               // score buckets per class
#define PT        20                 // cls entries per thread (5*float4)
#define NSTAG     8                  // LDS staging slots for mask rows

typedef unsigned long long u64;
typedef unsigned int u32;

typedef __attribute__((address_space(3))) u32 as3u32;
typedef __attribute__((address_space(1))) u32 as1u32;

// async global->LDS DMA: active lanes write 16B each at ldsBase + lane*16
__device__ __forceinline__ void row_load16(const u32* g, u64* lds) {
    __builtin_amdgcn_global_load_lds((const as1u32*)g, (as3u32*)(u32*)lds, 16, 0, 0);
}
__device__ __forceinline__ float readlane_f(float v, int lane) {
    return __int_as_float(__builtin_amdgcn_readlane(__float_as_int(v), lane));
}

// ================= 1) fused prep: init_out + transpose + build_mask =================
#define INIT_BLKS 1641               // ceil(5000*84/256)
#define TR_BX     157                // ceil(5000/32)
#define TR_BY     3                  // ceil(80/32)
#define TR_BLKS   (TR_BX * TR_BY)    // 471
#define MK_BLKS   (79 * 20)          // i-chunks x word-quads = 1580

__global__ __launch_bounds__(256) void prep(const float* __restrict__ boxes,
                                            const float4* __restrict__ boxes4,
                                            const float* __restrict__ cls,
                                            float* __restrict__ clsT,
                                            u64* __restrict__ mask,
                                            float* __restrict__ out) {
    __shared__ float tile[32][33];
    __shared__ float4 jb[4][64];
    __shared__ float  ja[4][64];

    int b = blockIdx.x;
    if (b < INIT_BLKS) {                         // ---- init out ----
        int i = b * 256 + threadIdx.x;
        if (i < N_ANCHORS * OUT_COLS) {
            int row = i / OUT_COLS, col = i - row * OUT_COLS;
            out[i] = (col < 4) ? boxes[row * 4 + col] : 0.0f;
        }
        return;
    }
    b -= INIT_BLKS;
    if (b < TR_BLKS) {                           // ---- transpose cls ----
        int bx_ = b % TR_BX, by_ = b / TR_BX;
        int j0 = bx_ * 32, c0 = by_ * 32;
        int tx = threadIdx.x & 31, ty = threadIdx.x >> 5;
        #pragma unroll
        for (int r = 0; r < 32; r += 8) {
            int j = j0 + ty + r, c = c0 + tx;
            tile[ty + r][tx] = (j < N_ANCHORS && c < N_CLASSES) ? cls[j * N_CLASSES + c] : 0.0f;
        }
        __syncthreads();
        #pragma unroll
        for (int r = 0; r < 32; r += 8) {
            int c = c0 + ty + r, j = j0 + tx;
            if (c < N_CLASSES && j < N_ANCHORS) clsT[(size_t)c * N_ANCHORS + j] = tile[tx][ty + r];
        }
        return;
    }
    b -= TR_BLKS;                                // ---- build mask (per-wave job) ----
    {
        int t = threadIdx.x & 63, wave = threadIdx.x >> 6;
        int ic = b / 20, wq = b % 20;
        int w = wq * 4 + wave;                   // word 0..79
        int j = w * 64 + t;
        if (j < N_ANCHORS) {
            float4 v = boxes4[j];
            jb[wave][t] = v; ja[wave][t] = (v.z - v.x) * (v.w - v.y);
        } else {
            jb[wave][t] = make_float4(3e8f, 3e8f, 3e8f, 3e8f); ja[wave][t] = 0.0f;
        }
        // same-wave LDS ops execute in order: no barrier needed
        int i = ic * 64 + t;
        if (i >= N_ANCHORS) return;
        float4 bi = boxes4[i];
        float ar = (bi.z - bi.x) * (bi.w - bi.y);
        u64 bits = 0ull;
        #pragma unroll
        for (int q = 0; q < 64; ++q) {
            float4 bj = jb[wave][q];
            float iw = fmaxf(fminf(bi.z, bj.z) - fmaxf(bi.x, bj.x), 0.0f);
            float ih = fmaxf(fminf(bi.w, bj.w) - fmaxf(bi.y, bj.y), 0.0f);
            float inter = iw * ih;
            if (3.0f * inter > ar + ja[wave][q]) bits |= (1ull << q);   // IoU > 0.5
        }
        mask[(size_t)i * NWORDS + w] = bits;
    }
}

// ================= 2) fused per-class sort + scan =================
__device__ __forceinline__ int bucket_of(float s) {
    float u = sqrtf(s);
    int b = (int)((u - 0.2236f) * 5275.0f);
    return min(max(b, 0), NB - 1);
}

__global__ __launch_bounds__(256) void sort_scan(const float* __restrict__ clsT,
                                                 const float4* __restrict__ boxes4,
                                                 const u64* __restrict__ mask,
                                                 float* __restrict__ out) {
    const int c = blockIdx.x;
    const int t = threadIdx.x;
    __shared__ u32 hist[NB];            // 16.4 KB
    __shared__ u32 wtot[4];
    __shared__ u64 lk[SORT_PAD];        // 40.4 KB sorted keys
    __shared__ u64 BM[NWORDS];          // 640 B suppressed bitmap
    __shared__ u64 stag[NSTAG * NWORDS];// 5.1 KB mask-row staging

    // ---------- sort phase (all 256 threads) ----------
    const float4* cp4 = (const float4*)(clsT + (size_t)c * N_ANCHORS);
    u32 sb[PT];
    #pragma unroll
    for (int k = 0; k < 5; ++k) {
        int j = k * 1024 + t * 4;
        float4 v = make_float4(0.f, 0.f, 0.f, 0.f);
        if (j < N_ANCHORS) v = cp4[k * 256 + t];
        sb[k * 4 + 0] = (v.x > SCORE_THR) ? __float_as_uint(v.x) : 0u;
        sb[k * 4 + 1] = (v.y > SCORE_THR) ? __float_as_uint(v.y) : 0u;
        sb[k * 4 + 2] = (v.z > SCORE_THR) ? __float_as_uint(v.z) : 0u;
        sb[k * 4 + 3] = (v.w > SCORE_THR) ? __float_as_uint(v.w) : 0u;
    }

    for (int b = t; b < NB; b += 256) hist[b] = 0u;
    if (t < NWORDS) BM[t] = 0ull;
    __syncthreads();

    #pragma unroll
    for (int m = 0; m < PT; ++m)
        if (sb[m]) atomicAdd(&hist[bucket_of(__uint_as_float(sb[m]))], 1u);
    __syncthreads();

    // exclusive prefix: thread owns 16 consecutive buckets
    const int base = t * 16;
    u32 vals[16];
    u32 run = 0;
    #pragma unroll
    for (int k = 0; k < 16; ++k) { run += hist[base + k]; vals[k] = run; }
    u32 x = run;
    const int lane6 = t & 63;
    #pragma unroll
    for (int off = 1; off < 64; off <<= 1) {
        u32 y = __shfl_up(x, off);
        if (lane6 >= off) x += y;
    }
    if (lane6 == 63) wtot[t >> 6] = x;
    __syncthreads();
    u32 woff = 0;
    for (int w = 0; w < (t >> 6); ++w) woff += wtot[w];
    const u32 exbase = woff + x - run;
    #pragma unroll
    for (int k = 0; k < 16; ++k)
        hist[base + k] = exbase + (k ? vals[k - 1] : 0u);   // start of bucket
    __syncthreads();

    #pragma unroll
    for (int m = 0; m < PT; ++m) {
        if (sb[m]) {
            int j = (m >> 2) * 1024 + t * 4 + (m & 3);
            u32 pos = atomicAdd(&hist[bucket_of(__uint_as_float(sb[m]))], 1u);
            lk[pos] = ((u64)sb[m] << 32) | (u32)(~(u32)j);
        }
    }
    __syncthreads();   // hist[b] now end of bucket b

    const int total = (int)hist[NB - 1];
    for (int v = total + t; v < SORT_PAD; v += 256) lk[v] = 0ull;
    for (int b = base; b < base + 16; ++b) {
        int s0 = b ? (int)hist[b - 1] : 0;
        int e  = (int)hist[b];
        for (int i = s0 + 1; i < e; ++i) {
            u64 key = lk[i];
            int q = i - 1;
            while (q >= s0 && lk[q] < key) { lk[q + 1] = lk[q]; --q; }
            lk[q + 1] = key;
        }
    }
    __syncthreads();

    // ---------- scan phase (wave 0 only) ----------
    if (t >= 64) return;
    const int lane = t;

    int kept = 0, pend = 0;
    u64 key = lk[lane];
    { u32 jj = key ? ~(u32)key : 0u; }
    float4 bx = boxes4[key ? ~(u32)key : 0u];
    u64 keyN; float4 bxN;

    for (int chunk = 0; chunk < NCHUNK; ++chunk) {
        bool valid = (key != 0ull);
        u64 vm = __ballot(valid);
        if (vm == 0ull) break;

        // flush staged rows from previous chunk (DMA had the whole keep loop as cover)
        if (pend) {
            __builtin_amdgcn_s_waitcnt(0);
            u64 bm0 = BM[lane];
            u64 bm1 = (lane < 16) ? BM[64 + lane] : 0ull;
            for (int r = 0; r < pend; ++r) {
                bm0 |= stag[r * NWORDS + lane];
                if (lane < 16) bm1 |= stag[r * NWORDS + 64 + lane];
            }
            BM[lane] = bm0;
            if (lane < 16) BM[64 + lane] = bm1;
            pend = 0;
        }

        u32 j = valid ? ~(u32)key : 0u;
        int W = (int)(j >> 6), bpos = (int)(j & 63u);
        float sc = __uint_as_float((u32)(key >> 32));
        float ar = (bx.z - bx.x) * (bx.w - bx.y);

        u64 word = BM[W];                      // ds gather
        bool alive = valid && !((word >> bpos) & 1ull);
        u64 rem = __ballot(alive);

        // prefetch next chunk (issued after the flush so its latency is covered by keep loop)
        keyN = 0ull; bxN = make_float4(0.f, 0.f, 0.f, 0.f);
        if (chunk + 1 < NCHUNK) {
            keyN = lk[(chunk + 1) * 64 + lane];
            bxN = boxes4[keyN ? ~(u32)keyN : 0u];
        }

        u64 km = 0ull; bool capped = false;
        while (rem) {
            int pos = __ffsll((long long)rem) - 1;
            km |= 1ull << pos;
            ++kept;
            u32 jk = (u32)__builtin_amdgcn_readlane((int)j, pos);
            if (lane < 40)                       // 40 lanes x 16B = 640B row
                row_load16((const u32*)(mask + (size_t)jk * NWORDS) + lane * 4,
                           &stag[pend * NWORDS]);
            ++pend;
            if (kept == MAX_BOXES) { capped = true; break; }
            if (pend == NSTAG) {                 // rare overflow flush
                __builtin_amdgcn_s_waitcnt(0);
                u64 bm0 = BM[lane];
                u64 bm1 = (lane < 16) ? BM[64 + lane] : 0ull;
                #pragma unroll
                for (int r = 0; r < NSTAG; ++r) {
                    bm0 |= stag[r * NWORDS + lane];
                    if (lane < 16) bm1 |= stag[r * NWORDS + 64 + lane];
                }
                BM[lane] = bm0;
                if (lane < 16) BM[64 + lane] = bm1;
                pend = 0;
            }
            float kx1 = readlane_f(bx.x, pos);
            float ky1 = readlane_f(bx.y, pos);
            float kx2 = readlane_f(bx.z, pos);
            float ky2 = readlane_f(bx.w, pos);
            float sAB = (kx2 - kx1) * (ky2 - ky1) + ar;     // A_keep + A_lane
            float iw = fmaxf(fminf(kx2, bx.z) - fmaxf(kx1, bx.x), 0.0f);
            float ih = fmaxf(fminf(ky2, bx.w) - fmaxf(ky1, bx.y), 0.0f);
            float inter = iw * ih;
            alive = alive && !(3.0f * inter > sAB);          // IoU > 0.5 (kills pos: IoU=1)
            rem = __ballot(alive);
        }

        if ((km >> lane) & 1ull) out[(size_t)j * OUT_COLS + 4 + c] = sc;
        if (capped) return;

        key = keyN; bx = bxN;
        if (__popcll(vm) < 64) break;   // sorted+packed: tail reached
    }
}

extern "C" void kernel_launch(void* const* d_in, const int* in_sizes, int n_in,
                              void* d_out, int out_size, void* d_ws, size_t ws_size,
                              hipStream_t stream) {
    const float* boxes = (const float*)d_in[0];
    const float* cls   = (const float*)d_in[1];
    float* out = (float*)d_out;

    char* w = (char*)d_ws;
    u64*   mask = (u64*)w;    w += (size_t)N_ANCHORS * NWORDS * 8;     // 3.20 MB
    float* clsT = (float*)w;                                           // 1.60 MB

    prep<<<INIT_BLKS + TR_BLKS + MK_BLKS, 256, 0, stream>>>(
        boxes, (const float4*)boxes, cls, clsT, mask, out);

    sort_scan<<<N_CLASSES, 256, 0, stream>>>(clsT, (const float4*)boxes, mask, out);
}